// Round 8
// baseline (87.656 us; speedup 1.0000x reference)
//
#include <hip/hip_runtime.h>

#define EPSF 1e-7f
#define TS2 72   // bf16 row stride: 64 + 8 pad (16B-aligned rows, bank-rotating)
#define OFS 68   // fp32 out-staging row stride

typedef __bf16 bf16;
typedef __attribute__((ext_vector_type(8))) __bf16 bf16x8;
typedef __attribute__((ext_vector_type(4))) __bf16 bf16x4;
typedef __attribute__((ext_vector_type(4))) float f32x4;

// Sum over each 16-lane group via DPP involutions. Zero LDS traffic.
__device__ __forceinline__ float dpp_sum16(float v) {
  int x;
  x = __builtin_amdgcn_update_dpp(0, __builtin_bit_cast(int, v), 0xB1, 0xf, 0xf, true);
  v += __builtin_bit_cast(float, x);                     // + lane^1
  x = __builtin_amdgcn_update_dpp(0, __builtin_bit_cast(int, v), 0x4E, 0xf, 0xf, true);
  v += __builtin_bit_cast(float, x);                     // + lane^2
  x = __builtin_amdgcn_update_dpp(0, __builtin_bit_cast(int, v), 0x141, 0xf, 0xf, true);
  v += __builtin_bit_cast(float, x);                     // + lane^7 (half mirror)
  x = __builtin_amdgcn_update_dpp(0, __builtin_bit_cast(int, v), 0x140, 0xf, 0xf, true);
  v += __builtin_bit_cast(float, x);                     // + lane^15 (mirror)
  return v;
}

// factor(dot) = acos(dot)/sqrt(1-dot^2) = theta/sin(theta), fused via
// A&S 4.4.45: acos(x)=sqrt(1-x)*P(x) for x>=0. Then
//   dot>=0: P(dot)*rsqrt(1+dot)
//   dot< 0: (pi*rsqrt(1-|dot|) - P(|dot|)) * rsqrt(1+|dot|)
// pp==1 and raw==dot away from the clamp; clamped i=0/it=0 case contributes
// O(1e-4*w) in both ref and here. 2 v_rsq + ~7 VALU.
__device__ __forceinline__ float fused_factor(float dot) {
  float ax = fabsf(dot);
  float q2 = __builtin_amdgcn_rsqf(1.0f + ax);
  float r2 = __builtin_amdgcn_rsqf(1.0f - ax);   // dot clamped -> 1-ax >= EPSF
  float pa = fmaf(fmaf(fmaf(-0.0187292994f, ax, 0.0742610070f), ax,
                       -0.2121144013f), ax, 1.5707288f);
  float sel = (dot < 0.0f) ? fmaf(3.14159265358979f, r2, -pa) : pa;
  return sel * q2;
}

// One block = one sample n; 4 waves; wave wv owns o-rows [16wv,16wv+16).
// GEMM1 (MFMA): dotT[o][i] = sum_dd a[o][dd]*x[i][dd]  (A=AC(Arow), B=xrf regs)
// GEMM2 (MFMA): G[o][dd]   = sum_i  c[i][o]*x[i][dd]   (A=AC(Ct),   B=xtf regs)
// BOTH MFMA B-operand sets are iteration-invariant and hoisted into 64 VGPRs
// after staging; the loop's only LDS ops are the AC round-trips (wave-private
// rows; Arow/Ct aliased -> same-wave in-order safe). This is the minimum LDS
// traffic: the C-layout -> A-layout transform per iteration is structurally
// an LDS transpose (packing writes just moves the scatter to the reads).
// wf is kept as packed bf16 pairs (8 VGPRs) to stay under the 128-VGPR cap
// for 4 waves/SIMD; bf16->f32 unpack (<<16) is exact.
__global__ __launch_bounds__(256, 4) void mfd_fc_mfma(
    const float* __restrict__ x, const float* __restrict__ wraw,
    float* __restrict__ out) {
  __shared__ __align__(16) char smem[3 * 64 * TS2 * sizeof(bf16)];  // 27648 B
  bf16* Xrow = (bf16*)smem;            // [i][dd]
  bf16* Xt   = Xrow + 64 * TS2;        // [dd][i]
  bf16* AC   = Xt + 64 * TS2;          // [o][dd] as Arow / [o][i] as Ct
  float* OutF = (float*)smem;          // epilogue: aliases Xrow+Xt (17408 B)

  const int n = blockIdx.x;
  const int tid = threadIdx.x;
  const int wv = tid >> 6;
  const int lane = tid & 63;
  const int ln15 = lane & 15;
  const int quad = lane >> 4;
  const int obase = 16 * wv + 4 * quad;
  const float* xn = x + (size_t)n * 4096;

  // ---- stage X -> Xrow (bf16), coalesced float4 loads ----
#pragma unroll
  for (int t = 0; t < 4; ++t) {
    int idx = tid + t * 256;  // float4 index
    int i = idx >> 4;
    int c4 = (idx & 15) << 2;
    float4 v = reinterpret_cast<const float4*>(xn)[idx];
    bf16x4 b;
    b[0] = (bf16)v.x; b[1] = (bf16)v.y; b[2] = (bf16)v.z; b[3] = (bf16)v.w;
    *reinterpret_cast<bf16x4*>(&Xrow[i * TS2 + c4]) = b;
  }

  // ---- per-wave softmax of wraw columns [obase..obase+3]; pack to bf16x2 ---
  unsigned int wfp[4][2];  // [t][r>>1]: (bf16(w[r even]) | bf16(w[r odd])<<16)
  {
    float wf[4][4];
    float cs[4] = {0.f, 0.f, 0.f, 0.f};
#pragma unroll
    for (int t = 0; t < 4; ++t) {
      float4 wr = *reinterpret_cast<const float4*>(&wraw[(16 * t + ln15) * 64 + obase]);
      wf[t][0] = __expf(wr.x); wf[t][1] = __expf(wr.y);
      wf[t][2] = __expf(wr.z); wf[t][3] = __expf(wr.w);
#pragma unroll
      for (int r = 0; r < 4; ++r) cs[r] += wf[t][r];
    }
#pragma unroll
    for (int r = 0; r < 4; ++r) {
      float inv = __builtin_amdgcn_rcpf(dpp_sum16(cs[r]));
#pragma unroll
      for (int t = 0; t < 4; ++t) wf[t][r] *= inv;
    }
#pragma unroll
    for (int t = 0; t < 4; ++t)
#pragma unroll
      for (int rr = 0; rr < 2; ++rr) {
        unsigned short lo = __builtin_bit_cast(unsigned short, (bf16)wf[t][2 * rr]);
        unsigned short hi = __builtin_bit_cast(unsigned short, (bf16)wf[t][2 * rr + 1]);
        wfp[t][rr] = (unsigned int)lo | ((unsigned int)hi << 16);
      }
  }

  // ---- a := x0 (fp32; dd = 16t+ln15, same value for all r) ----
  float a_reg[4][4];
#pragma unroll
  for (int t = 0; t < 4; ++t) {
    float v = xn[16 * t + ln15];
#pragma unroll
    for (int r = 0; r < 4; ++r) a_reg[t][r] = v;
  }
#pragma unroll
  for (int t = 0; t < 4; ++t)
#pragma unroll
    for (int r = 0; r < 4; ++r)
      AC[(obase + r) * TS2 + 16 * t + ln15] = (bf16)a_reg[t][r];

  __syncthreads();  // Xrow complete

  // ---- build Xt from Xrow (u16 column reads = pair-broadcast) ----
  {
    int dd = tid & 63, ih = tid >> 6;  // i-range [16*ih, 16*ih+16)
    bf16 tmp[16];
#pragma unroll
    for (int j = 0; j < 16; ++j) tmp[j] = Xrow[(16 * ih + j) * TS2 + dd];
    *reinterpret_cast<bf16x8*>(&Xt[dd * TS2 + 16 * ih]) =
        *reinterpret_cast<bf16x8*>(&tmp[0]);
    *reinterpret_cast<bf16x8*>(&Xt[dd * TS2 + 16 * ih + 8]) =
        *reinterpret_cast<bf16x8*>(&tmp[8]);
  }
  __syncthreads();  // Xt complete

  // ---- hoist ALL loop-invariant MFMA B-fragments into registers ----
  bf16x8 xrf[4][2];  // GEMM1 B: Xrow[(16t+ln15)][ks*32 + quad*8 ..]
  bf16x8 xtf[4][2];  // GEMM2 B: Xt  [(16t+ln15)][ks*32 + quad*8 ..]
#pragma unroll
  for (int t = 0; t < 4; ++t)
#pragma unroll
    for (int ks = 0; ks < 2; ++ks) {
      xrf[t][ks] = *reinterpret_cast<const bf16x8*>(
          &Xrow[(16 * t + ln15) * TS2 + ks * 32 + quad * 8]);
      xtf[t][ks] = *reinterpret_cast<const bf16x8*>(
          &Xt[(16 * t + ln15) * TS2 + ks * 32 + quad * 8]);
    }

  const bf16* acbase = &AC[(16 * wv + ln15) * TS2];

  for (int it = 0; it < 3; ++it) {
    // ---- GEMM1: dotT[o][i] (B from registers) ----
    f32x4 acc[4] = {f32x4{0,0,0,0}, f32x4{0,0,0,0}, f32x4{0,0,0,0}, f32x4{0,0,0,0}};
#pragma unroll
    for (int ks = 0; ks < 2; ++ks) {
      bf16x8 af = *reinterpret_cast<const bf16x8*>(&acbase[ks * 32 + quad * 8]);
#pragma unroll
      for (int t = 0; t < 4; ++t)
        acc[t] = __builtin_amdgcn_mfma_f32_16x16x32_bf16(af, xrf[t][ks], acc[t], 0, 0, 0);
    }

    // ---- elementwise: c = w * fused_factor(dot); Arow rows become Ct ----
    float sd[4] = {0.f, 0.f, 0.f, 0.f};
#pragma unroll
    for (int t = 0; t < 4; ++t) {
#pragma unroll
      for (int r = 0; r < 4; ++r) {
        float raw = acc[t][r];
        float dot = __builtin_amdgcn_fmed3f(raw, -1.0f + EPSF, 1.0f - EPSF);
        // exact bf16->f32 unpack of the packed weight
        unsigned int wb = (r & 1) ? (wfp[t][r >> 1] & 0xffff0000u)
                                  : (wfp[t][r >> 1] << 16);
        float wv_ = __builtin_bit_cast(float, wb);
        bf16 cb = (bf16)(wv_ * fused_factor(dot));
        AC[(obase + r) * TS2 + 16 * t + ln15] = cb;  // safe alias (wave-private)
        sd[r] = fmaf((float)cb, dot, sd[r]);
      }
    }
#pragma unroll
    for (int r = 0; r < 4; ++r) sd[r] = dpp_sum16(sd[r]);

    // ---- GEMM2: G[o][dd] (B from registers) ----
    f32x4 g[4] = {f32x4{0,0,0,0}, f32x4{0,0,0,0}, f32x4{0,0,0,0}, f32x4{0,0,0,0}};
#pragma unroll
    for (int ks = 0; ks < 2; ++ks) {
      bf16x8 af = *reinterpret_cast<const bf16x8*>(&acbase[ks * 32 + quad * 8]);
#pragma unroll
      for (int t = 0; t < 4; ++t)
        g[t] = __builtin_amdgcn_mfma_f32_16x16x32_bf16(af, xtf[t][ks], g[t], 0, 0, 0);
    }

    // ---- grad = G - sdot*a ; exp map with native trans ops ----
    float gn2[4] = {0.f, 0.f, 0.f, 0.f};
#pragma unroll
    for (int t = 0; t < 4; ++t)
#pragma unroll
      for (int r = 0; r < 4; ++r) {
        float v = g[t][r] - sd[r] * a_reg[t][r];
        g[t][r] = v;
        gn2[r] = fmaf(v, v, gn2[r]);
      }
#pragma unroll
    for (int r = 0; r < 4; ++r) {
      float nrm = __builtin_amdgcn_sqrtf(dpp_sum16(gn2[r]));
      float rev = nrm * 0.15915494309189535f;     // v_sin/v_cos take revolutions
      float sn_ = __builtin_amdgcn_sinf(rev);
      float cn  = __builtin_amdgcn_cosf(rev);
      float sn = (nrm < EPSF) ? 1.0f : sn_ * __builtin_amdgcn_rcpf(nrm);
#pragma unroll
      for (int t = 0; t < 4; ++t)
        a_reg[t][r] = fmaf(cn, a_reg[t][r], sn * g[t][r]);
    }
    if (it < 2) {
#pragma unroll
      for (int t = 0; t < 4; ++t)
#pragma unroll
        for (int r = 0; r < 4; ++r)
          AC[(obase + r) * TS2 + 16 * t + ln15] = (bf16)a_reg[t][r];
    }
  }

  // ---- epilogue: LDS fp32 transpose -> coalesced float4 stores ----
  __syncthreads();  // all waves done with Xrow/Xt before aliasing as OutF
#pragma unroll
  for (int t = 0; t < 4; ++t)
#pragma unroll
    for (int r = 0; r < 4; ++r)
      OutF[(obase + r) * OFS + 16 * t + ln15] = a_reg[t][r];
  __syncthreads();
  float* outn = out + (size_t)n * 4096;
#pragma unroll
  for (int t = 0; t < 4; ++t) {
    int idx = tid + t * 256;
    int row = idx >> 4, col4 = (idx & 15) << 2;
    float4 v = *reinterpret_cast<const float4*>(&OutF[row * OFS + col4]);
    reinterpret_cast<float4*>(outn)[idx] = v;
  }
}

extern "C" void kernel_launch(void* const* d_in, const int* in_sizes, int n_in,
                              void* d_out, int out_size, void* d_ws, size_t ws_size,
                              hipStream_t stream) {
  const float* x = (const float*)d_in[0];    // (B,L,64,64) fp32, unit rows
  const float* wraw = (const float*)d_in[1]; // (64,64) fp32
  float* out = (float*)d_out;                // (B,L,64,64) fp32
  (void)d_ws; (void)ws_size;

  int N = in_sizes[0] / 4096;  // B*L = 1024
  mfd_fc_mfma<<<N, 256, 0, stream>>>(x, wraw, out);
}

// Round 9
// 83.714 us; speedup vs baseline: 1.0471x; 1.0471x over previous
//
#include <hip/hip_runtime.h>

#define EPSF 1e-7f
#define TS2 72   // bf16 row stride: 64 + 8 pad (16B-aligned rows, bank-rotating)
#define OFS 68   // fp32 out-staging row stride

typedef __bf16 bf16;
typedef __attribute__((ext_vector_type(8))) __bf16 bf16x8;
typedef __attribute__((ext_vector_type(4))) __bf16 bf16x4;
typedef __attribute__((ext_vector_type(4))) float f32x4;

// Sum over each 16-lane group via DPP involutions. Zero LDS traffic.
__device__ __forceinline__ float dpp_sum16(float v) {
  int x;
  x = __builtin_amdgcn_update_dpp(0, __builtin_bit_cast(int, v), 0xB1, 0xf, 0xf, true);
  v += __builtin_bit_cast(float, x);                     // + lane^1
  x = __builtin_amdgcn_update_dpp(0, __builtin_bit_cast(int, v), 0x4E, 0xf, 0xf, true);
  v += __builtin_bit_cast(float, x);                     // + lane^2
  x = __builtin_amdgcn_update_dpp(0, __builtin_bit_cast(int, v), 0x141, 0xf, 0xf, true);
  v += __builtin_bit_cast(float, x);                     // + lane^7 (half mirror)
  x = __builtin_amdgcn_update_dpp(0, __builtin_bit_cast(int, v), 0x140, 0xf, 0xf, true);
  v += __builtin_bit_cast(float, x);                     // + lane^15 (mirror)
  return v;
}

// factor(dot) = acos(dot)/sqrt(1-dot^2) = theta/sin(theta), fused via
// A&S 4.4.45: acos(x)=sqrt(1-x)*P(x) for x>=0. Then
//   dot>=0: P(dot)*rsqrt(1+dot)
//   dot< 0: (pi*rsqrt(1-|dot|) - P(|dot|)) * rsqrt(1+|dot|)
// pp==1 and raw==dot away from the clamp; clamped i=0/it=0 case contributes
// O(1e-4*w) in both ref and here. 2 v_rsq + ~7 VALU.
__device__ __forceinline__ float fused_factor(float dot) {
  float ax = fabsf(dot);
  float q2 = __builtin_amdgcn_rsqf(1.0f + ax);
  float r2 = __builtin_amdgcn_rsqf(1.0f - ax);   // dot clamped -> 1-ax >= EPSF
  float pa = fmaf(fmaf(fmaf(-0.0187292994f, ax, 0.0742610070f), ax,
                       -0.2121144013f), ax, 1.5707288f);
  float sel = (dot < 0.0f) ? fmaf(3.14159265358979f, r2, -pa) : pa;
  return sel * q2;
}

// One block = one sample n; 4 waves; wave wv owns o-rows [16wv,16wv+16).
// GEMM1 (MFMA): dotT[o][i] = sum_dd a[o][dd]*x[i][dd]  (A=AC(Arow), B=xrf regs)
// GEMM2 (MFMA): G[o][dd]   = sum_i  c[i][o]*x[i][dd]   (A=AC(Ct),   B=Xt)
// GEMM1 B-fragments (Xrow) are iteration-invariant -> hoisted into 32 VGPRs.
// (GEMM2's Xt fragments stay in LDS: hoisting them too raised VGPR pressure
// past the 128/4-wave cap's comfort zone and measured neutral-to-worse, R8.)
// AC holds Arow then Ct in the SAME storage: rows are wave-private and every
// Arow read precedes the first Ct write in program order (same-wave LDS ops
// are in-order), so aliasing is safe. LDS = 27648 B -> 4 blocks/CU, 16
// waves/CU (grid 1024 = 4 x 256 CUs exactly).
// Barrier schedule: [stage Xrow] sync [Xt build + Xrow->reg + GEMM1/elem it0]
// sync-once [GEMM2 it0; iters 1,2 barrier-free].
__global__ __launch_bounds__(256, 4) void mfd_fc_mfma(
    const float* __restrict__ x, const float* __restrict__ wraw,
    float* __restrict__ out) {
  __shared__ __align__(16) char smem[3 * 64 * TS2 * sizeof(bf16)];  // 27648 B
  bf16* Xrow = (bf16*)smem;            // [i][dd]
  bf16* Xt   = Xrow + 64 * TS2;        // [dd][i]
  bf16* AC   = Xt + 64 * TS2;          // [o][dd] as Arow / [o][i] as Ct
  float* OutF = (float*)smem;          // epilogue: aliases Xrow+Xt (17408 B)

  const int n = blockIdx.x;
  const int tid = threadIdx.x;
  const int wv = tid >> 6;
  const int lane = tid & 63;
  const int ln15 = lane & 15;
  const int quad = lane >> 4;
  const int obase = 16 * wv + 4 * quad;
  const float* xn = x + (size_t)n * 4096;

  // ---- stage X -> Xrow (bf16), coalesced float4 loads ----
#pragma unroll
  for (int t = 0; t < 4; ++t) {
    int idx = tid + t * 256;  // float4 index
    int i = idx >> 4;
    int c4 = (idx & 15) << 2;
    float4 v = reinterpret_cast<const float4*>(xn)[idx];
    bf16x4 b;
    b[0] = (bf16)v.x; b[1] = (bf16)v.y; b[2] = (bf16)v.z; b[3] = (bf16)v.w;
    *reinterpret_cast<bf16x4*>(&Xrow[i * TS2 + c4]) = b;
  }

  // ---- per-wave softmax of wraw columns [obase..obase+3] ----
  float wf[4][4];
  {
    float cs[4] = {0.f, 0.f, 0.f, 0.f};
#pragma unroll
    for (int t = 0; t < 4; ++t) {
      float4 wr = *reinterpret_cast<const float4*>(&wraw[(16 * t + ln15) * 64 + obase]);
      wf[t][0] = __expf(wr.x); wf[t][1] = __expf(wr.y);
      wf[t][2] = __expf(wr.z); wf[t][3] = __expf(wr.w);
#pragma unroll
      for (int r = 0; r < 4; ++r) cs[r] += wf[t][r];
    }
#pragma unroll
    for (int r = 0; r < 4; ++r) {
      float inv = __builtin_amdgcn_rcpf(dpp_sum16(cs[r]));
#pragma unroll
      for (int t = 0; t < 4; ++t) wf[t][r] *= inv;
    }
  }

  // ---- a := x0 (fp32; dd = 16t+ln15, same value for all r) ----
  float a_reg[4][4];
#pragma unroll
  for (int t = 0; t < 4; ++t) {
    float v = xn[16 * t + ln15];
#pragma unroll
    for (int r = 0; r < 4; ++r) a_reg[t][r] = v;
  }
#pragma unroll
  for (int t = 0; t < 4; ++t)
#pragma unroll
    for (int r = 0; r < 4; ++r)
      AC[(obase + r) * TS2 + 16 * t + ln15] = (bf16)a_reg[t][r];

  __syncthreads();  // Xrow complete

  // ---- build Xt from Xrow (u16 column reads = pair-broadcast) ----
  {
    int dd = tid & 63, ih = tid >> 6;  // i-range [16*ih, 16*ih+16)
    bf16 tmp[16];
#pragma unroll
    for (int j = 0; j < 16; ++j) tmp[j] = Xrow[(16 * ih + j) * TS2 + dd];
    *reinterpret_cast<bf16x8*>(&Xt[dd * TS2 + 16 * ih]) =
        *reinterpret_cast<bf16x8*>(&tmp[0]);
    *reinterpret_cast<bf16x8*>(&Xt[dd * TS2 + 16 * ih + 8]) =
        *reinterpret_cast<bf16x8*>(&tmp[8]);
  }
  // NOTE: no barrier yet — GEMM1/elementwise of it=0 only touch Xrow/AC.

  // ---- hoist GEMM1 B-fragments (Xrow is loop-invariant): 8 x bf16x8 ----
  bf16x8 xrf[4][2];
#pragma unroll
  for (int t = 0; t < 4; ++t)
#pragma unroll
    for (int ks = 0; ks < 2; ++ks)
      xrf[t][ks] = *reinterpret_cast<const bf16x8*>(
          &Xrow[(16 * t + ln15) * TS2 + ks * 32 + quad * 8]);

  const bf16* acbase = &AC[(16 * wv + ln15) * TS2];

  for (int it = 0; it < 3; ++it) {
    // ---- GEMM1: dotT[o][i] (B from registers) ----
    f32x4 acc[4] = {f32x4{0,0,0,0}, f32x4{0,0,0,0}, f32x4{0,0,0,0}, f32x4{0,0,0,0}};
#pragma unroll
    for (int ks = 0; ks < 2; ++ks) {
      bf16x8 af = *reinterpret_cast<const bf16x8*>(&acbase[ks * 32 + quad * 8]);
#pragma unroll
      for (int t = 0; t < 4; ++t)
        acc[t] = __builtin_amdgcn_mfma_f32_16x16x32_bf16(af, xrf[t][ks], acc[t], 0, 0, 0);
    }

    // ---- elementwise: c = w * fused_factor(dot); Arow rows become Ct ----
    float sd[4] = {0.f, 0.f, 0.f, 0.f};
#pragma unroll
    for (int t = 0; t < 4; ++t) {
#pragma unroll
      for (int r = 0; r < 4; ++r) {
        float raw = acc[t][r];
        float dot = __builtin_amdgcn_fmed3f(raw, -1.0f + EPSF, 1.0f - EPSF);
        bf16 cb = (bf16)(wf[t][r] * fused_factor(dot));
        AC[(obase + r) * TS2 + 16 * t + ln15] = cb;  // safe alias (wave-private)
        sd[r] = fmaf((float)cb, dot, sd[r]);
      }
    }
#pragma unroll
    for (int r = 0; r < 4; ++r) sd[r] = dpp_sum16(sd[r]);

    if (it == 0) __syncthreads();  // Xt complete (hidden behind GEMM1+elem)

    // ---- GEMM2: G[o][dd] ----
    f32x4 g[4] = {f32x4{0,0,0,0}, f32x4{0,0,0,0}, f32x4{0,0,0,0}, f32x4{0,0,0,0}};
#pragma unroll
    for (int ks = 0; ks < 2; ++ks) {
      bf16x8 af = *reinterpret_cast<const bf16x8*>(&acbase[ks * 32 + quad * 8]);
#pragma unroll
      for (int t = 0; t < 4; ++t) {
        bf16x8 bfr = *reinterpret_cast<const bf16x8*>(
            &Xt[(16 * t + ln15) * TS2 + ks * 32 + quad * 8]);
        g[t] = __builtin_amdgcn_mfma_f32_16x16x32_bf16(af, bfr, g[t], 0, 0, 0);
      }
    }

    // ---- grad = G - sdot*a ; exp map with native trans ops ----
    float gn2[4] = {0.f, 0.f, 0.f, 0.f};
#pragma unroll
    for (int t = 0; t < 4; ++t)
#pragma unroll
      for (int r = 0; r < 4; ++r) {
        float v = g[t][r] - sd[r] * a_reg[t][r];
        g[t][r] = v;
        gn2[r] = fmaf(v, v, gn2[r]);
      }
#pragma unroll
    for (int r = 0; r < 4; ++r) {
      float nrm = __builtin_amdgcn_sqrtf(dpp_sum16(gn2[r]));
      float rev = nrm * 0.15915494309189535f;     // v_sin/v_cos take revolutions
      float sn_ = __builtin_amdgcn_sinf(rev);
      float cn  = __builtin_amdgcn_cosf(rev);
      float sn = (nrm < EPSF) ? 1.0f : sn_ * __builtin_amdgcn_rcpf(nrm);
#pragma unroll
      for (int t = 0; t < 4; ++t)
        a_reg[t][r] = fmaf(cn, a_reg[t][r], sn * g[t][r]);
    }
    if (it < 2) {
#pragma unroll
      for (int t = 0; t < 4; ++t)
#pragma unroll
        for (int r = 0; r < 4; ++r)
          AC[(obase + r) * TS2 + 16 * t + ln15] = (bf16)a_reg[t][r];
    }
  }

  // ---- epilogue: LDS fp32 transpose -> coalesced float4 stores ----
  __syncthreads();  // all waves done with Xt before aliasing as OutF
#pragma unroll
  for (int t = 0; t < 4; ++t)
#pragma unroll
    for (int r = 0; r < 4; ++r)
      OutF[(obase + r) * OFS + 16 * t + ln15] = a_reg[t][r];
  __syncthreads();
  float* outn = out + (size_t)n * 4096;
#pragma unroll
  for (int t = 0; t < 4; ++t) {
    int idx = tid + t * 256;
    int row = idx >> 4, col4 = (idx & 15) << 2;
    float4 v = *reinterpret_cast<const float4*>(&OutF[row * OFS + col4]);
    reinterpret_cast<float4*>(outn)[idx] = v;
  }
}

extern "C" void kernel_launch(void* const* d_in, const int* in_sizes, int n_in,
                              void* d_out, int out_size, void* d_ws, size_t ws_size,
                              hipStream_t stream) {
  const float* x = (const float*)d_in[0];    // (B,L,64,64) fp32, unit rows
  const float* wraw = (const float*)d_in[1]; // (64,64) fp32
  float* out = (float*)d_out;                // (B,L,64,64) fp32
  (void)d_ws; (void)ws_size;

  int N = in_sizes[0] / 4096;  // B*L = 1024
  mfd_fc_mfma<<<N, 256, 0, stream>>>(x, wraw, out);
}